// Round 1
// baseline (155.150 us; speedup 1.0000x reference)
//
#include <hip/hip_runtime.h>
#include <hip/hip_bf16.h>

// Problem constants
#define HH 512
#define BB 8192
#define KK 1536            // 3*H concatenated reduction dim
#define MM 2049            // 4H+1
#define MP 2176            // M padded to 17*128

typedef __bf16 bhalf;
typedef __bf16 bf16x8 __attribute__((ext_vector_type(8)));
typedef float  f32x4  __attribute__((ext_vector_type(4)));

typedef __attribute__((address_space(1))) void* as1_t;
typedef __attribute__((address_space(3))) void* as3_t;

// ---------------------------------------------------------------------------
// prep_x: Xt[n][k] = scale(n,k) * src(k)[k_local][n], cast to bf16.
//   k in [0,512):    (1-z[n]) * h
//   k in [512,1024): z[n]     * h_top
//   k in [1024,1536):zb[n]    * h_bottom
// LDS-tiled 64x64 transpose; 512 % 64 == 0 so each block hits one source.
// ---------------------------------------------------------------------------
__global__ __launch_bounds__(256) void prep_x(
    const float* __restrict__ h, const float* __restrict__ h_top,
    const float* __restrict__ h_bottom, const float* __restrict__ z,
    const float* __restrict__ zb, bhalf* __restrict__ Xt)
{
    __shared__ float tile[64][65];
    const int tx = threadIdx.x & 63;
    const int ty = threadIdx.x >> 6;          // 0..3
    const int k0 = blockIdx.x * 64;           // 0..1472
    const int n0 = blockIdx.y * 64;
    const int n  = n0 + tx;

    const float* src; int kr; float scale;
    if (k0 < 512)       { src = h;        kr = k0;        scale = 1.f - z[n]; }
    else if (k0 < 1024) { src = h_top;    kr = k0 - 512;  scale = z[n]; }
    else                { src = h_bottom; kr = k0 - 1024; scale = zb[n]; }

    #pragma unroll
    for (int r = ty; r < 64; r += 4)
        tile[r][tx] = src[(size_t)(kr + r) * BB + n] * scale;
    __syncthreads();
    #pragma unroll
    for (int r = ty; r < 64; r += 4)
        Xt[(size_t)(n0 + r) * KK + (k0 + tx)] = (bhalf)tile[tx][r];
}

// ---------------------------------------------------------------------------
// prep_w: Wc (MP x KK) bf16 = [U11 | U21 | W01], zero-padded rows >= MM.
// ---------------------------------------------------------------------------
__global__ __launch_bounds__(256) void prep_w(
    const float* __restrict__ U11, const float* __restrict__ U21,
    const float* __restrict__ W01, bhalf* __restrict__ Wc)
{
    const int k = blockIdx.x * 256 + threadIdx.x;   // gridDim.x = 6 -> 1536
    const int m = blockIdx.y;                       // 0..2175
    float v = 0.f;
    if (m < MM) {
        if (k < 512)       v = U11[(size_t)m * 512 + k];
        else if (k < 1024) v = U21[(size_t)m * 512 + (k - 512)];
        else               v = W01[(size_t)m * 512 + (k - 1024)];
    }
    Wc[(size_t)m * KK + k] = (bhalf)v;
}

// ---------------------------------------------------------------------------
// gemm_fs: fs = Wc @ Xt^T + bias.  A = Wc (MP x KK) row-major bf16,
// B^T = Xt (BB x KK) row-major bf16.  m97 structure: 128x128 tile, BK=64,
// 4 waves (2x2), 4x4 16x16x32 fragments per wave, global_load_lds width 16.
// ---------------------------------------------------------------------------
__global__ __launch_bounds__(256) void gemm_fs(
    const bhalf* __restrict__ Wc, const bhalf* __restrict__ Xt,
    const float* __restrict__ bias, float* __restrict__ fs)
{
    __shared__ bhalf As[128 * 64];
    __shared__ bhalf Bs[128 * 64];

    const int tid  = threadIdx.x;
    const int lane = tid & 63;
    const int w    = tid >> 6;               // 0..3
    const int wr   = (w >> 1) * 64;          // wave row offset in tile
    const int wc   = (w & 1) * 64;           // wave col offset in tile
    const int lr   = lane & 15;
    const int lk   = (lane >> 4) * 8;        // k sub-block 0/8/16/24
    const int n0   = blockIdx.x * 128;
    const int m0   = blockIdx.y * 128;

    f32x4 acc[4][4] = {};

    for (int kt = 0; kt < KK / 64; ++kt) {
        const int k0 = kt * 64;
        #pragma unroll
        for (int i = 0; i < 4; ++i) {
            const int chunk = i * 256 + tid;      // 0..1023, 16B each
            const int row   = chunk >> 3;         // 0..127
            const int cb    = (chunk & 7) * 8;    // 0..56
            __builtin_amdgcn_global_load_lds(
                (as1_t)(void*)(Wc + (size_t)(m0 + row) * KK + k0 + cb),
                (as3_t)(void*)(As + chunk * 8), 16, 0, 0);
            __builtin_amdgcn_global_load_lds(
                (as1_t)(void*)(Xt + (size_t)(n0 + row) * KK + k0 + cb),
                (as3_t)(void*)(Bs + chunk * 8), 16, 0, 0);
        }
        __syncthreads();

        #pragma unroll
        for (int kk = 0; kk < 64; kk += 32) {
            bf16x8 a[4], b[4];
            #pragma unroll
            for (int m = 0; m < 4; ++m)
                a[m] = *(const bf16x8*)&As[(wr + m * 16 + lr) * 64 + kk + lk];
            #pragma unroll
            for (int nn = 0; nn < 4; ++nn)
                b[nn] = *(const bf16x8*)&Bs[(wc + nn * 16 + lr) * 64 + kk + lk];
            #pragma unroll
            for (int m = 0; m < 4; ++m)
                #pragma unroll
                for (int nn = 0; nn < 4; ++nn)
                    acc[m][nn] = __builtin_amdgcn_mfma_f32_16x16x32_bf16(
                        a[m], b[nn], acc[m][nn], 0, 0, 0);
        }
        __syncthreads();
    }

    // store fs (+bias); D mapping: col = lane&15, row = (lane>>4)*4 + reg
    #pragma unroll
    for (int m = 0; m < 4; ++m) {
        #pragma unroll
        for (int r = 0; r < 4; ++r) {
            const int row = m0 + wr + m * 16 + (lane >> 4) * 4 + r;
            if (row < MM) {
                const float bv = bias[row];
                #pragma unroll
                for (int nn = 0; nn < 4; ++nn) {
                    const int col = n0 + wc + nn * 16 + lr;
                    fs[(size_t)row * BB + col] = acc[m][nn][r] + bv;
                }
            }
        }
    }
}

// ---------------------------------------------------------------------------
// epilogue: gates + blend.  float4 over batch.
// ---------------------------------------------------------------------------
__device__ __forceinline__ float sigmf(float x)    { return 1.f / (1.f + __expf(-x)); }
__device__ __forceinline__ float tanhfast(float x) { return 2.f / (1.f + __expf(-2.f * x)) - 1.f; }

__global__ __launch_bounds__(256) void epilogue_k(
    const float* __restrict__ fs, const float* __restrict__ c,
    const float* __restrict__ h, const float* __restrict__ z,
    const float* __restrict__ zb, float* __restrict__ out)
{
    const int t = blockIdx.x * 256 + threadIdx.x;   // 0..1048575
    const int j = t >> 11;                          // hidden idx
    const int n = (t & 2047) << 2;                  // batch idx (x4)
    const size_t HB = (size_t)HH * BB;
    const size_t base = (size_t)j * BB + n;

    float4 f4  = *(const float4*)(fs + base);
    float4 i4  = *(const float4*)(fs + base + HB);
    float4 o4  = *(const float4*)(fs + base + 2 * HB);
    float4 g4  = *(const float4*)(fs + base + 3 * HB);
    float4 c4  = *(const float4*)(c + base);
    float4 h4  = *(const float4*)(h + base);
    float4 z4  = *(const float4*)(z + n);
    float4 zb4 = *(const float4*)(zb + n);

    const float* fp  = (const float*)&f4;
    const float* ip  = (const float*)&i4;
    const float* op  = (const float*)&o4;
    const float* gp  = (const float*)&g4;
    const float* cp  = (const float*)&c4;
    const float* hp  = (const float*)&h4;
    const float* zp  = (const float*)&z4;
    const float* zbp = (const float*)&zb4;

    float4 hn, cn;
    float* hnp = (float*)&hn;
    float* cnp = (float*)&cn;

    #pragma unroll
    for (int q = 0; q < 4; ++q) {
        const float zq = zp[q], zbq = zbp[q];
        const float fg = sigmf(fp[q]);
        const float og = sigmf(op[q]);
        const float ig = sigmf(ip[q]) * tanhfast(gp[q]);
        const float cq = zq * ig + (1.f - zq) * (1.f - zbq) * cp[q]
                       + (1.f - zq) * zbq * (fg * cp[q] + ig);
        const float tc = tanhfast(cq);
        const float hq = (zq + (1.f - zq) * zbq) * og * tc
                       + (1.f - zq) * (1.f - zbq) * hp[q];
        cnp[q] = cq;
        hnp[q] = hq;
    }
    *(float4*)(out + base)      = hn;
    *(float4*)(out + HB + base) = cn;
}

__global__ __launch_bounds__(256) void zhat_k(
    const float* __restrict__ fs, float* __restrict__ out)
{
    const int n = blockIdx.x * 256 + threadIdx.x;
    if (n < BB) {
        const float v = (fs[(size_t)(MM - 1) * BB + n] + 1.f) * 0.5f;
        out[(size_t)2 * HH * BB + n] = fminf(fmaxf(v, 0.f), 1.f);
    }
}

// ---------------------------------------------------------------------------
extern "C" void kernel_launch(void* const* d_in, const int* in_sizes, int n_in,
                              void* d_out, int out_size, void* d_ws, size_t ws_size,
                              hipStream_t stream) {
    const float* c    = (const float*)d_in[0];
    const float* hb   = (const float*)d_in[1];
    const float* h    = (const float*)d_in[2];
    const float* ht   = (const float*)d_in[3];
    const float* z    = (const float*)d_in[4];
    const float* zb   = (const float*)d_in[5];
    const float* U11  = (const float*)d_in[6];
    const float* U21  = (const float*)d_in[7];
    const float* W01  = (const float*)d_in[8];
    const float* bias = (const float*)d_in[9];
    float* out = (float*)d_out;

    // workspace layout (needs ~99 MB):
    //   Xt: 8192*1536 bf16 = 25165824 B
    //   Wc: 2176*1536 bf16 =  6684672 B
    //   fs: 2049*8192 f32  = 67141632 B
    char* ws = (char*)d_ws;
    bhalf* Xt = (bhalf*)ws;
    bhalf* Wc = (bhalf*)(ws + 25165824);
    float* fs = (float*)(ws + 25165824 + 6684672);

    prep_x   <<<dim3(24, 128), 256, 0, stream>>>(h, ht, hb, z, zb, Xt);
    prep_w   <<<dim3(6, MP),   256, 0, stream>>>(U11, U21, W01, Wc);
    gemm_fs  <<<dim3(64, 17),  256, 0, stream>>>(Wc, Xt, bias, fs);
    epilogue_k<<<4096, 256, 0, stream>>>(fs, c, h, z, zb, out);
    zhat_k   <<<32, 256, 0, stream>>>(fs, out);
}

// Round 2
// 103.903 us; speedup vs baseline: 1.4932x; 1.4932x over previous
//
#include <hip/hip_runtime.h>
#include <hip/hip_bf16.h>

#define HH 512
#define BB 8192
#define KK 1536            // 3*H concatenated reduction dim
#define NT 24              // K tiles of 64
#define HB 4194304         // 512*8192

typedef __bf16 bhalf;
typedef __bf16 bf16x8 __attribute__((ext_vector_type(8)));
typedef float  f32x4  __attribute__((ext_vector_type(4)));

typedef __attribute__((address_space(1))) void* as1_t;
typedef __attribute__((address_space(3))) void* as3_t;

#define GLDS(src, dst) __builtin_amdgcn_global_load_lds((as1_t)(void*)(src), (as3_t)(void*)(dst), 16, 0, 0)
#define VM_BAR(n) asm volatile("s_waitcnt vmcnt(" #n ")\n\ts_barrier" ::: "memory")
#define BAR()     asm volatile("s_barrier" ::: "memory")

// ---------------------------------------------------------------------------
// prep_x: Xt[n][k] = scale(n,k) * src(k)[k_local][n], cast to bf16.
// ---------------------------------------------------------------------------
__global__ __launch_bounds__(256) void prep_x(
    const float* __restrict__ h, const float* __restrict__ h_top,
    const float* __restrict__ h_bottom, const float* __restrict__ z,
    const float* __restrict__ zb, bhalf* __restrict__ Xt)
{
    __shared__ float tile[64][65];
    const int tx = threadIdx.x & 63;
    const int ty = threadIdx.x >> 6;
    const int k0 = blockIdx.x * 64;
    const int n0 = blockIdx.y * 64;
    const int n  = n0 + tx;

    const float* src; int kr; float scale;
    if (k0 < 512)       { src = h;        kr = k0;        scale = 1.f - z[n]; }
    else if (k0 < 1024) { src = h_top;    kr = k0 - 512;  scale = z[n]; }
    else                { src = h_bottom; kr = k0 - 1024; scale = zb[n]; }

    #pragma unroll
    for (int r = ty; r < 64; r += 4)
        tile[r][tx] = src[(size_t)(kr + r) * BB + n] * scale;
    __syncthreads();
    #pragma unroll
    for (int r = ty; r < 64; r += 4)
        Xt[(size_t)(n0 + r) * KK + (k0 + tx)] = (bhalf)tile[tx][r];
}

// ---------------------------------------------------------------------------
// prep_w: Wc (2048 x KK) bf16, gate-interleaved rows: m' = 4*j + g maps to
// original row g*512 + j  (g: 0=f,1=i,2=o,3=g).  z_hat row (2048) excluded.
// ---------------------------------------------------------------------------
__global__ __launch_bounds__(256) void prep_w(
    const float* __restrict__ U11, const float* __restrict__ U21,
    const float* __restrict__ W01, bhalf* __restrict__ Wc)
{
    const int k  = blockIdx.x * 256 + threadIdx.x;   // gridDim.x = 6
    const int mp = blockIdx.y;                       // 0..2047
    const int orig = (mp & 3) * 512 + (mp >> 2);
    float v;
    if (k < 512)       v = U11[(size_t)orig * 512 + k];
    else if (k < 1024) v = U21[(size_t)orig * 512 + (k - 512)];
    else               v = W01[(size_t)orig * 512 + (k - 1024)];
    Wc[(size_t)mp * KK + k] = (bhalf)v;
}

// ---------------------------------------------------------------------------
__device__ __forceinline__ float sigmf(float x)    { return 1.f / (1.f + __expf(-x)); }
__device__ __forceinline__ float tanhfast(float x) { return 2.f / (1.f + __expf(-2.f * x)) - 1.f; }

// ---------------------------------------------------------------------------
// gemm_fused: 256x256 tile, BK=64, 8 waves (2M x 4N), counted-vmcnt pipeline,
// K-sliced [256][32] LDS halves (conflict-free linear layout), fused gate
// epilogue writing h_new/c_new directly.
// Grid: 256 blocks (8 M-tiles x 32 N-tiles) = exactly 1 block/CU.
// ---------------------------------------------------------------------------
__global__ __launch_bounds__(512, 2) void gemm_fused(
    const bhalf* __restrict__ Wc, const bhalf* __restrict__ Xt,
    const float* __restrict__ bias, const float* __restrict__ c_in,
    const float* __restrict__ h_in, const float* __restrict__ z,
    const float* __restrict__ zb, float* __restrict__ out)
{
    __shared__ bhalf As[2 * 256 * 64];   // 64 KB: [buf][slice][256][32]
    __shared__ bhalf Bs[2 * 256 * 64];   // 64 KB

    const int tid  = threadIdx.x;
    const int lane = tid & 63;
    const int wid  = tid >> 6;          // 0..7
    const int wm   = wid >> 2;          // 0..1
    const int wn   = wid & 3;           // 0..3
    const int lr   = lane & 15;
    const int hi   = lane >> 4;         // 0..3

    // XCD-aware swizzle: 256 blocks, XCD = bid%8 gets one M-panel (L2-resident)
    const int f  = blockIdx.x;
    const int mt = f & 7;               // 0..7
    const int nt = f >> 3;              // 0..31
    const int m0 = mt * 256, n0 = nt * 256;

    // staging constants: chunk c = tid + 512q; row = c>>2, colchunk = c&3
    const bhalf* gA = Wc + (size_t)(m0 + (tid >> 2)) * KK + (tid & 3) * 8;
    const bhalf* gB = Xt + (size_t)(n0 + (tid >> 2)) * KK + (tid & 3) * 8;
    bhalf* lA = As + tid * 8;
    bhalf* lB = Bs + tid * 8;

#define STAGE_TILE(t, beta) do {                                              \
        const bhalf* sa = gA + (size_t)(t) * 64;                              \
        const bhalf* sb = gB + (size_t)(t) * 64;                              \
        bhalf* la = lA + (beta) * 16384;                                      \
        bhalf* lb = lB + (beta) * 16384;                                      \
        GLDS(sa,               la);            /* A slice0 rows 0..127  */    \
        GLDS(sa + 128 * KK,    la + 4096);     /* A slice0 rows 128..255 */   \
        GLDS(sa + 32,          la + 8192);     /* A slice1 rows 0..127  */    \
        GLDS(sa + 128 * KK + 32, la + 12288);  /* A slice1 rows 128..255 */   \
        GLDS(sb,               lb);                                           \
        GLDS(sb + 128 * KK,    lb + 4096);                                    \
        GLDS(sb + 32,          lb + 8192);                                    \
        GLDS(sb + 128 * KK + 32, lb + 12288);                                 \
    } while (0)

    f32x4 acc[8][4] = {};

    STAGE_TILE(0, 0);

    for (int t = 0; t < NT; ++t) {
        const int beta = t & 1;
        if (t + 1 < NT) {
            STAGE_TILE(t + 1, beta ^ 1);
            VM_BAR(8);                 // tile t landed; tile t+1's 8 loads in flight
        } else {
            VM_BAR(0);
        }
        const bhalf* Ab = As + beta * 16384;
        const bhalf* Bb = Bs + beta * 16384;

        // ---- K slice 0 (k = 0..31 of this tile) ----
        {
            bf16x8 a[8], b[4];
            #pragma unroll
            for (int m = 0; m < 8; ++m)
                a[m] = *(const bf16x8*)&Ab[(wm * 128 + m * 16 + lr) * 32 + hi * 8];
            #pragma unroll
            for (int n = 0; n < 4; ++n)
                b[n] = *(const bf16x8*)&Bb[(wn * 64 + n * 16 + lr) * 32 + hi * 8];
            __builtin_amdgcn_s_setprio(1);
            #pragma unroll
            for (int m = 0; m < 8; ++m)
                #pragma unroll
                for (int n = 0; n < 4; ++n)
                    acc[m][n] = __builtin_amdgcn_mfma_f32_16x16x32_bf16(a[m], b[n], acc[m][n], 0, 0, 0);
            __builtin_amdgcn_s_setprio(0);
        }
        // ---- K slice 1 (k = 32..63) ----
        {
            bf16x8 a[8], b[4];
            #pragma unroll
            for (int m = 0; m < 8; ++m)
                a[m] = *(const bf16x8*)&Ab[8192 + (wm * 128 + m * 16 + lr) * 32 + hi * 8];
            #pragma unroll
            for (int n = 0; n < 4; ++n)
                b[n] = *(const bf16x8*)&Bb[8192 + (wn * 64 + n * 16 + lr) * 32 + hi * 8];
            __builtin_amdgcn_s_setprio(1);
            #pragma unroll
            for (int m = 0; m < 8; ++m)
                #pragma unroll
                for (int n = 0; n < 4; ++n)
                    acc[m][n] = __builtin_amdgcn_mfma_f32_16x16x32_bf16(a[m], b[n], acc[m][n], 0, 0, 0);
            __builtin_amdgcn_s_setprio(0);
        }
        BAR();   // all waves done reading buf beta before next STAGE overwrites it
    }

    // ---- fused epilogue: each f32x4 acc[mi][ni] = (f,i,o,g) for hidden j ----
    const int colbase = n0 + wn * 64 + lr;
    float zc[4], zbc[4];
    #pragma unroll
    for (int ni = 0; ni < 4; ++ni) {
        zc[ni]  = z[colbase + ni * 16];
        zbc[ni] = zb[colbase + ni * 16];
    }
    #pragma unroll
    for (int mi = 0; mi < 8; ++mi) {
        const int j = (m0 >> 2) + wm * 32 + mi * 4 + hi;   // 0..511
        const float bf_ = bias[j];
        const float bi_ = bias[512 + j];
        const float bo_ = bias[1024 + j];
        const float bg_ = bias[1536 + j];
        #pragma unroll
        for (int ni = 0; ni < 4; ++ni) {
            const int col = colbase + ni * 16;
            const size_t idx = (size_t)j * BB + col;
            const float cv = c_in[idx];
            const float hv = h_in[idx];
            const float fv = sigmf(acc[mi][ni][0] + bf_);
            const float iv = sigmf(acc[mi][ni][1] + bi_);
            const float ov = sigmf(acc[mi][ni][2] + bo_);
            const float gv = tanhfast(acc[mi][ni][3] + bg_);
            const float ig = iv * gv;
            const float zq = zc[ni], zbq = zbc[ni];
            const float cn = zq * ig + (1.f - zq) * (1.f - zbq) * cv
                           + (1.f - zq) * zbq * (fv * cv + ig);
            const float tc = tanhfast(cn);
            const float hn = (zq + (1.f - zq) * zbq) * ov * tc
                           + (1.f - zq) * (1.f - zbq) * hv;
            out[idx]      = hn;
            out[HB + idx] = cn;
        }
    }
}

// ---------------------------------------------------------------------------
// zhat_gemv: row 2048 (z_hat) as a 1-row GEMV over Xt; one wave per column.
// ---------------------------------------------------------------------------
__global__ __launch_bounds__(256) void zhat_gemv(
    const bhalf* __restrict__ Xt, const float* __restrict__ U11,
    const float* __restrict__ U21, const float* __restrict__ W01,
    const float* __restrict__ bias, float* __restrict__ out)
{
    const int gw   = (blockIdx.x * 256 + threadIdx.x) >> 6;  // 0..8191 (column)
    const int lane = threadIdx.x & 63;
    const bhalf* xp = Xt + (size_t)gw * KK;
    float s = 0.f;
    #pragma unroll
    for (int i = 0; i < 12; ++i) {
        const int k = i * 128 + lane * 2;
        float w0, w1;
        if (k < 512)       { w0 = U11[2048 * 512 + k];          w1 = U11[2048 * 512 + k + 1]; }
        else if (k < 1024) { w0 = U21[2048 * 512 + (k - 512)];  w1 = U21[2048 * 512 + (k - 511)]; }
        else               { w0 = W01[2048 * 512 + (k - 1024)]; w1 = W01[2048 * 512 + (k - 1023)]; }
        s += (float)xp[k] * w0 + (float)xp[k + 1] * w1;
    }
    #pragma unroll
    for (int off = 32; off; off >>= 1) s += __shfl_down(s, off);
    if (lane == 0) {
        const float v = (s + bias[2048] + 1.f) * 0.5f;
        out[(size_t)2 * HB + gw] = fminf(fmaxf(v, 0.f), 1.f);
    }
}

// ---------------------------------------------------------------------------
extern "C" void kernel_launch(void* const* d_in, const int* in_sizes, int n_in,
                              void* d_out, int out_size, void* d_ws, size_t ws_size,
                              hipStream_t stream) {
    const float* c    = (const float*)d_in[0];
    const float* hb   = (const float*)d_in[1];
    const float* h    = (const float*)d_in[2];
    const float* ht   = (const float*)d_in[3];
    const float* z    = (const float*)d_in[4];
    const float* zb   = (const float*)d_in[5];
    const float* U11  = (const float*)d_in[6];
    const float* U21  = (const float*)d_in[7];
    const float* W01  = (const float*)d_in[8];
    const float* bias = (const float*)d_in[9];
    float* out = (float*)d_out;

    // workspace: Xt 8192*1536 bf16 = 25165824 B; Wc 2048*1536 bf16 = 6291456 B
    char* ws = (char*)d_ws;
    bhalf* Xt = (bhalf*)ws;
    bhalf* Wc = (bhalf*)(ws + 25165824);

    prep_x    <<<dim3(24, 128), 256, 0, stream>>>(h, ht, hb, z, zb, Xt);
    prep_w    <<<dim3(6, 2048), 256, 0, stream>>>(U11, U21, W01, Wc);
    gemm_fused<<<256, 512, 0, stream>>>(Wc, Xt, bias, c, h, z, zb, out);
    zhat_gemv <<<2048, 256, 0, stream>>>(Xt, U11, U21, W01, bias, out);
}

// Round 3
// 82.534 us; speedup vs baseline: 1.8798x; 1.2589x over previous
//
#include <hip/hip_runtime.h>
#include <hip/hip_bf16.h>

#define HH 512
#define BB 8192
#define KK 1536
#define NT 48              // K tiles of 32
#define HB 4194304         // 512*8192
#define BLOB 8192          // bhalf per 16KB blob

typedef __bf16 bhalf;
typedef __bf16 bf16x8 __attribute__((ext_vector_type(8)));
typedef float  f32x4  __attribute__((ext_vector_type(4)));

typedef __attribute__((address_space(1))) void* as1_t;
typedef __attribute__((address_space(3))) void* as3_t;

#define GLDS(src, dst) __builtin_amdgcn_global_load_lds((as1_t)(void*)(src), (as3_t)(void*)(dst), 16, 0, 0)
#define SBAR() asm volatile("s_barrier" ::: "memory")
#define VM8()  asm volatile("s_waitcnt vmcnt(8)" ::: "memory")
#define VM4()  asm volatile("s_waitcnt vmcnt(4)" ::: "memory")
#define VM0()  asm volatile("s_waitcnt vmcnt(0)" ::: "memory")

// Packed blob layout (both A and B): blob = one (256-row, 32-k) tile = 16 KB.
// slot s in [0,1024): rb = s>>6 (16-row block), w = s&63,
//   lr = w>>2, hi = (w&3) ^ (lr>>2)   [XOR involution -> 2 lanes/bank-group]
// element (row rb*16+lr, k hi*8+e) lives at byte s*16 + e*2.

// ---------------------------------------------------------------------------
// prep_x: pack scaled+transposed+bf16 X into blobs [nt][kt].
// ---------------------------------------------------------------------------
__global__ __launch_bounds__(256) void prep_x(
    const float* __restrict__ h, const float* __restrict__ ht,
    const float* __restrict__ hb, const float* __restrict__ z,
    const float* __restrict__ zb, bhalf* __restrict__ XtP)
{
    __shared__ float tile[32][257];
    const int tid = threadIdx.x;
    const int kt  = blockIdx.x;          // 0..47
    const int nt  = blockIdx.y;          // 0..31
    const int n   = nt * 256 + tid;
    const int kb  = kt * 32;

    const float* src; int kr; float scale;
    if (kb < 512)       { src = h;  kr = kb;        scale = 1.f - z[n]; }
    else if (kb < 1024) { src = ht; kr = kb - 512;  scale = z[n]; }
    else                { src = hb; kr = kb - 1024; scale = zb[n]; }

    #pragma unroll
    for (int kk = 0; kk < 32; ++kk)
        tile[kk][tid] = src[(size_t)(kr + kk) * BB + n] * scale;
    __syncthreads();

    bhalf* blob = XtP + (size_t)(nt * NT + kt) * BLOB;
    #pragma unroll
    for (int q = 0; q < 4; ++q) {
        const int s  = q * 256 + tid;
        const int rb = s >> 6, w = s & 63;
        const int lrr = w >> 2, hh = (w & 3) ^ (lrr >> 2);
        const int nloc = rb * 16 + lrr, kloc = hh * 8;
        bf16x8 r;
        #pragma unroll
        for (int e = 0; e < 8; ++e) r[e] = (bhalf)tile[kloc + e][nloc];
        *(bf16x8*)(blob + s * 8) = r;
    }
}

// ---------------------------------------------------------------------------
// prep_w: pack gate-interleaved weights into blobs [mt][kt]; source-coalesced.
// orig row o (g = o>>9, j = o&511) -> interleaved row mp = 4j + g.
// ---------------------------------------------------------------------------
__global__ __launch_bounds__(256) void prep_w(
    const float* __restrict__ U11, const float* __restrict__ U21,
    const float* __restrict__ W01, bhalf* __restrict__ WcP)
{
    const int o    = blockIdx.x * 4 + (threadIdx.x >> 6);   // 0..2047
    const int lane = threadIdx.x & 63;
    const int g = o >> 9, j = o & 511;
    const int mp = 4 * j + g;
    const int mt = mp >> 8, rb = (mp >> 4) & 15, lrr = mp & 15;

    #pragma unroll
    for (int p = 0; p < 3; ++p) {
        const float* src = (p == 0) ? U11 : (p == 1) ? U21 : W01;
        const float* rp  = src + (size_t)o * 512 + lane * 8;
        float4 v0 = *(const float4*)rp;
        float4 v1 = *(const float4*)(rp + 4);
        bf16x8 r;
        r[0]=(bhalf)v0.x; r[1]=(bhalf)v0.y; r[2]=(bhalf)v0.z; r[3]=(bhalf)v0.w;
        r[4]=(bhalf)v1.x; r[5]=(bhalf)v1.y; r[6]=(bhalf)v1.z; r[7]=(bhalf)v1.w;
        const int kt = p * 16 + (lane >> 2);
        const int hh = lane & 3;
        const int slot = lrr * 4 + (hh ^ (lrr >> 2));
        *(bf16x8*)(WcP + (size_t)(mt * NT + kt) * BLOB + rb * 512 + slot * 8) = r;
    }
}

// ---------------------------------------------------------------------------
__device__ __forceinline__ float sigmf(float x)    { return 1.f / (1.f + __expf(-x)); }
__device__ __forceinline__ float tanhfast(float x) { return 2.f / (1.f + __expf(-2.f * x)) - 1.f; }

__device__ __forceinline__ void compute_tile(
    const bhalf* __restrict__ Ab, const bhalf* __restrict__ Bb,
    f32x4 (&acc)[8][4])
{
    bf16x8 bfr[4], afr[4];
    #pragma unroll
    for (int n = 0; n < 4; ++n) bfr[n] = *(const bf16x8*)(Bb + n * 512);
    #pragma unroll
    for (int m = 0; m < 4; ++m) afr[m] = *(const bf16x8*)(Ab + m * 512);
    __builtin_amdgcn_s_setprio(1);
    #pragma unroll
    for (int m = 0; m < 4; ++m)
        #pragma unroll
        for (int n = 0; n < 4; ++n)
            acc[m][n] = __builtin_amdgcn_mfma_f32_16x16x32_bf16(afr[m], bfr[n], acc[m][n], 0, 0, 0);
    __builtin_amdgcn_s_setprio(0);
    #pragma unroll
    for (int m = 0; m < 4; ++m) afr[m] = *(const bf16x8*)(Ab + (4 + m) * 512);
    __builtin_amdgcn_s_setprio(1);
    #pragma unroll
    for (int m = 0; m < 4; ++m)
        #pragma unroll
        for (int n = 0; n < 4; ++n)
            acc[4 + m][n] = __builtin_amdgcn_mfma_f32_16x16x32_bf16(afr[m], bfr[n], acc[4 + m][n], 0, 0, 0);
    __builtin_amdgcn_s_setprio(0);
}

// ---------------------------------------------------------------------------
// gemm_fused: BM=BN=256, BK=32, 8 waves (2Mx4N), 4 LDS buffers, depth-3
// counted-vmcnt prefetch, pre-swizzled packed operands, fused gate epilogue.
// Grid 256 blocks = 1/CU; XCD-chunked swizzle (each XCD: 4 nt x all mt).
// ---------------------------------------------------------------------------
__global__ __launch_bounds__(512, 2) void gemm_fused(
    const bhalf* __restrict__ WcP, const bhalf* __restrict__ XtP,
    const float* __restrict__ bias, const float* __restrict__ c_in,
    const float* __restrict__ h_in, const float* __restrict__ z,
    const float* __restrict__ zb, float* __restrict__ out)
{
    __shared__ bhalf As[4][BLOB];
    __shared__ bhalf Bs[4][BLOB];

    const int tid  = threadIdx.x;
    const int lane = tid & 63;
    const int wid  = tid >> 6;
    const int wm   = wid >> 2, wn = wid & 3;
    const int lr   = lane & 15, hi = lane >> 4;
    const int soff = (lr * 4 + (hi ^ (lr >> 2))) * 8;   // bhalf units

    const int xcd = blockIdx.x & 7;
    const int i   = blockIdx.x >> 3;
    const int mt  = i & 7;
    const int nt  = xcd * 4 + (i >> 3);
    const int m0 = mt * 256, n0 = nt * 256;

    const bhalf* gA = WcP + (size_t)mt * (NT * BLOB) + tid * 8;
    const bhalf* gB = XtP + (size_t)nt * (NT * BLOB) + tid * 8;

#define STAGE(t) do {                                                   \
        const bhalf* sa_ = gA + (size_t)(t) * BLOB;                     \
        const bhalf* sb_ = gB + (size_t)(t) * BLOB;                     \
        bhalf* da_ = &As[(t) & 3][tid * 8];                             \
        bhalf* db_ = &Bs[(t) & 3][tid * 8];                             \
        GLDS(sa_, da_); GLDS(sa_ + 4096, da_ + 4096);                   \
        GLDS(sb_, db_); GLDS(sb_ + 4096, db_ + 4096);                   \
    } while (0)

    f32x4 acc[8][4] = {};

    STAGE(0); STAGE(1); STAGE(2);

    for (int tt = 0; tt < 44; tt += 4) {
        #pragma unroll
        for (int u = 0; u < 4; ++u) {
            VM8(); SBAR();
            STAGE(tt + u + 3);                        // buf (u+3)&3 static
            compute_tile(&As[u][wm * 4096 + soff], &Bs[u][wn * 2048 + soff], acc);
        }
    }
    // tiles 44..47 (stage 47 at t=44; drain counts 8/8/4/0)
    VM8(); SBAR(); STAGE(47);
    compute_tile(&As[0][wm * 4096 + soff], &Bs[0][wn * 2048 + soff], acc);
    VM8(); SBAR();
    compute_tile(&As[1][wm * 4096 + soff], &Bs[1][wn * 2048 + soff], acc);
    VM4(); SBAR();
    compute_tile(&As[2][wm * 4096 + soff], &Bs[2][wn * 2048 + soff], acc);
    VM0(); SBAR();
    compute_tile(&As[3][wm * 4096 + soff], &Bs[3][wn * 2048 + soff], acc);

    // ---- fused gate epilogue: acc[mi][ni][r] = gate r of hidden j ----
    const int colbase = n0 + wn * 64 + lr;
    float zc[4], zbc[4];
    #pragma unroll
    for (int ni = 0; ni < 4; ++ni) {
        zc[ni]  = z[colbase + ni * 16];
        zbc[ni] = zb[colbase + ni * 16];
    }
    #pragma unroll
    for (int mi = 0; mi < 8; ++mi) {
        const int j = (m0 >> 2) + wm * 32 + mi * 4 + hi;
        const float bf_ = bias[j];
        const float bi_ = bias[512 + j];
        const float bo_ = bias[1024 + j];
        const float bg_ = bias[1536 + j];
        #pragma unroll
        for (int ni = 0; ni < 4; ++ni) {
            const int col = colbase + ni * 16;
            const size_t idx = (size_t)j * BB + col;
            const float cv = c_in[idx];
            const float hv = h_in[idx];
            const float fv = sigmf(acc[mi][ni][0] + bf_);
            const float iv = sigmf(acc[mi][ni][1] + bi_);
            const float ov = sigmf(acc[mi][ni][2] + bo_);
            const float gv = tanhfast(acc[mi][ni][3] + bg_);
            const float ig = iv * gv;
            const float zq = zc[ni], zbq = zbc[ni];
            const float cn = zq * ig + (1.f - zq) * (1.f - zbq) * cv
                           + (1.f - zq) * zbq * (fv * cv + ig);
            const float tc = tanhfast(cn);
            const float hn = (zq + (1.f - zq) * zbq) * ov * tc
                           + (1.f - zq) * (1.f - zbq) * hv;
            out[idx]      = hn;
            out[HB + idx] = cn;
        }
    }
}

// ---------------------------------------------------------------------------
// zhat: row 2048 GEMV over packed Xt (bf16). 256 blocks x 32 cols,
// 8 k-groups per column, LDS reduce.
// ---------------------------------------------------------------------------
__global__ __launch_bounds__(256) void zhat_k(
    const bhalf* __restrict__ XtP, const float* __restrict__ U11,
    const float* __restrict__ U21, const float* __restrict__ W01,
    const float* __restrict__ bias, float* __restrict__ out)
{
    __shared__ float wlds[1536];
    __shared__ float red[8][32];
    const int tid = threadIdx.x;
    for (int idx = tid; idx < 1536; idx += 256) {
        float v;
        if (idx < 512)       v = U11[1048576 + idx];
        else if (idx < 1024) v = U21[1048576 + idx - 512];
        else                 v = W01[1048576 + idx - 1024];
        wlds[idx] = v;
    }
    __syncthreads();

    const int col = tid & 31, kg = tid >> 5;
    const int n = blockIdx.x * 32 + col;
    const int nt = n >> 8, rb = (n >> 4) & 15, lrr = n & 15;
    const bhalf* base = XtP + (size_t)nt * (NT * BLOB) + rb * 512;

    float acc = 0.f;
    for (int kt = kg * 6; kt < kg * 6 + 6; ++kt) {
        #pragma unroll
        for (int hh = 0; hh < 4; ++hh) {
            const int slot = lrr * 4 + (hh ^ (lrr >> 2));
            bf16x8 v = *(const bf16x8*)(base + (size_t)kt * BLOB + slot * 8);
            #pragma unroll
            for (int e = 0; e < 8; ++e)
                acc += (float)v[e] * wlds[kt * 32 + hh * 8 + e];
        }
    }
    red[kg][col] = acc;
    __syncthreads();
    if (tid < 32) {
        float s = 0.f;
        #pragma unroll
        for (int k2 = 0; k2 < 8; ++k2) s += red[k2][tid];
        const float v = (s + bias[2048] + 1.f) * 0.5f;
        out[(size_t)2 * HB + blockIdx.x * 32 + tid] = fminf(fmaxf(v, 0.f), 1.f);
    }
}

// ---------------------------------------------------------------------------
extern "C" void kernel_launch(void* const* d_in, const int* in_sizes, int n_in,
                              void* d_out, int out_size, void* d_ws, size_t ws_size,
                              hipStream_t stream) {
    const float* c    = (const float*)d_in[0];
    const float* hb   = (const float*)d_in[1];
    const float* h    = (const float*)d_in[2];
    const float* ht   = (const float*)d_in[3];
    const float* z    = (const float*)d_in[4];
    const float* zb   = (const float*)d_in[5];
    const float* U11  = (const float*)d_in[6];
    const float* U21  = (const float*)d_in[7];
    const float* W01  = (const float*)d_in[8];
    const float* bias = (const float*)d_in[9];
    float* out = (float*)d_out;

    // ws: XtP 32*48*16KB = 25165824 B; WcP 8*48*16KB = 6291456 B
    char* ws = (char*)d_ws;
    bhalf* XtP = (bhalf*)ws;
    bhalf* WcP = (bhalf*)(ws + 25165824);

    prep_x    <<<dim3(48, 32), 256, 0, stream>>>(h, ht, hb, z, zb, XtP);
    prep_w    <<<512, 256, 0, stream>>>(U11, U21, W01, WcP);
    gemm_fused<<<256, 512, 0, stream>>>(WcP, XtP, bias, c, h, z, zb, out);
    zhat_k    <<<256, 256, 0, stream>>>(XtP, U11, U21, W01, bias, out);
}

// Round 4
// 81.792 us; speedup vs baseline: 1.8969x; 1.0091x over previous
//
#include <hip/hip_runtime.h>
#include <hip/hip_bf16.h>

#define HH 512
#define BB 8192
#define KK 1536
#define NT 48              // K tiles of 32
#define HB 4194304         // 512*8192
#define BLOB 8192          // bhalf per 16KB blob

typedef __bf16 bhalf;
typedef __bf16 bf16x8 __attribute__((ext_vector_type(8)));
typedef float  f32x4  __attribute__((ext_vector_type(4)));

typedef __attribute__((address_space(1))) void* as1_t;
typedef __attribute__((address_space(3))) void* as3_t;

#define GLDS(src, dst) __builtin_amdgcn_global_load_lds((as1_t)(void*)(src), (as3_t)(void*)(dst), 16, 0, 0)
#define SBAR() asm volatile("s_barrier" ::: "memory")
#define VM8()  asm volatile("s_waitcnt vmcnt(8)" ::: "memory")
#define VM4()  asm volatile("s_waitcnt vmcnt(4)" ::: "memory")
#define VM0()  asm volatile("s_waitcnt vmcnt(0)" ::: "memory")

// Packed blob layout (k-major, conflict-free): blob = one (256-row, 32-k)
// tile = 16 KB.  slot s = rb*64 + hi*16 + lr  (rb = 16-row block, hi = k-group,
// lr = row-in-block).  Element (row rb*16+lr, k hi*8+e) at bhalf offset s*8+e.
// A wave's fragment read (lanes: lr = l&15, hi = l>>4) hits byte
// rb*1024 + hi*256 + lr*16: each consecutive 8-lane group covers banks 0..31
// exactly once -> zero bank conflicts.

// ---------------------------------------------------------------------------
// prep_x: pack scaled+transposed+bf16 X into blobs [nt][kt].
// ---------------------------------------------------------------------------
__global__ __launch_bounds__(256) void prep_x(
    const float* __restrict__ h, const float* __restrict__ ht,
    const float* __restrict__ hb, const float* __restrict__ z,
    const float* __restrict__ zb, bhalf* __restrict__ XtP)
{
    __shared__ float tile[32][257];
    const int tid = threadIdx.x;
    const int kt  = blockIdx.x;          // 0..47
    const int nt  = blockIdx.y;          // 0..31
    const int n   = nt * 256 + tid;
    const int kb  = kt * 32;

    const float* src; int kr; float scale;
    if (kb < 512)       { src = h;  kr = kb;        scale = 1.f - z[n]; }
    else if (kb < 1024) { src = ht; kr = kb - 512;  scale = z[n]; }
    else                { src = hb; kr = kb - 1024; scale = zb[n]; }

    #pragma unroll
    for (int kk = 0; kk < 32; ++kk)
        tile[kk][tid] = src[(size_t)(kr + kk) * BB + n] * scale;
    __syncthreads();

    bhalf* blob = XtP + (size_t)(nt * NT + kt) * BLOB;
    #pragma unroll
    for (int q = 0; q < 4; ++q) {
        const int s  = q * 256 + tid;
        const int rb = s >> 6, w = s & 63;
        const int hh = w >> 4, lrr = w & 15;      // slot = rb*64 + hh*16 + lrr
        const int nloc = rb * 16 + lrr, kloc = hh * 8;
        bf16x8 r;
        #pragma unroll
        for (int e = 0; e < 8; ++e) r[e] = (bhalf)tile[kloc + e][nloc];
        *(bf16x8*)(blob + s * 8) = r;
    }
}

// ---------------------------------------------------------------------------
// prep_w: pack gate-interleaved weights into blobs [mt][kt]; source-coalesced.
// orig row o (g = o>>9, j = o&511) -> interleaved row mp = 4j + g.
// ---------------------------------------------------------------------------
__global__ __launch_bounds__(256) void prep_w(
    const float* __restrict__ U11, const float* __restrict__ U21,
    const float* __restrict__ W01, bhalf* __restrict__ WcP)
{
    const int o    = blockIdx.x * 4 + (threadIdx.x >> 6);   // 0..2047
    const int lane = threadIdx.x & 63;
    const int g = o >> 9, j = o & 511;
    const int mp = 4 * j + g;
    const int mt = mp >> 8, rb = (mp >> 4) & 15, lrr = mp & 15;

    #pragma unroll
    for (int p = 0; p < 3; ++p) {
        const float* src = (p == 0) ? U11 : (p == 1) ? U21 : W01;
        const float* rp  = src + (size_t)o * 512 + lane * 8;
        float4 v0 = *(const float4*)rp;
        float4 v1 = *(const float4*)(rp + 4);
        bf16x8 r;
        r[0]=(bhalf)v0.x; r[1]=(bhalf)v0.y; r[2]=(bhalf)v0.z; r[3]=(bhalf)v0.w;
        r[4]=(bhalf)v1.x; r[5]=(bhalf)v1.y; r[6]=(bhalf)v1.z; r[7]=(bhalf)v1.w;
        const int kt = p * 16 + (lane >> 2);
        const int hh = lane & 3;
        *(bf16x8*)(WcP + (size_t)(mt * NT + kt) * BLOB
                   + rb * 512 + hh * 128 + lrr * 8) = r;
    }
}

// ---------------------------------------------------------------------------
__device__ __forceinline__ float sigmf(float x)    { return 1.f / (1.f + __expf(-x)); }
__device__ __forceinline__ float tanhfast(float x) { return 2.f / (1.f + __expf(-2.f * x)) - 1.f; }

__device__ __forceinline__ void compute_tile(
    const bhalf* __restrict__ Ab, const bhalf* __restrict__ Bb,
    f32x4 (&acc)[8][4])
{
    bf16x8 bfr[4], afr[4];
    #pragma unroll
    for (int n = 0; n < 4; ++n) bfr[n] = *(const bf16x8*)(Bb + n * 512);
    #pragma unroll
    for (int m = 0; m < 4; ++m) afr[m] = *(const bf16x8*)(Ab + m * 512);
    __builtin_amdgcn_s_setprio(1);
    #pragma unroll
    for (int m = 0; m < 4; ++m)
        #pragma unroll
        for (int n = 0; n < 4; ++n)
            acc[m][n] = __builtin_amdgcn_mfma_f32_16x16x32_bf16(afr[m], bfr[n], acc[m][n], 0, 0, 0);
    __builtin_amdgcn_s_setprio(0);
    #pragma unroll
    for (int m = 0; m < 4; ++m) afr[m] = *(const bf16x8*)(Ab + (4 + m) * 512);
    __builtin_amdgcn_s_setprio(1);
    #pragma unroll
    for (int m = 0; m < 4; ++m)
        #pragma unroll
        for (int n = 0; n < 4; ++n)
            acc[4 + m][n] = __builtin_amdgcn_mfma_f32_16x16x32_bf16(afr[m], bfr[n], acc[4 + m][n], 0, 0, 0);
    __builtin_amdgcn_s_setprio(0);
}

// ---------------------------------------------------------------------------
// gemm_fused: BM=BN=256, BK=32, 8 waves (2Mx4N), 4 LDS buffers, depth-3
// counted-vmcnt prefetch, k-major packed operands (0 bank conflicts),
// fused gate epilogue.  Grid 256 blocks = 1/CU; XCD-chunked swizzle.
// ---------------------------------------------------------------------------
__global__ __launch_bounds__(512, 2) void gemm_fused(
    const bhalf* __restrict__ WcP, const bhalf* __restrict__ XtP,
    const float* __restrict__ bias, const float* __restrict__ c_in,
    const float* __restrict__ h_in, const float* __restrict__ z,
    const float* __restrict__ zb, float* __restrict__ out)
{
    __shared__ bhalf As[4][BLOB];
    __shared__ bhalf Bs[4][BLOB];

    const int tid  = threadIdx.x;
    const int lane = tid & 63;
    const int wid  = tid >> 6;
    const int wm   = wid >> 2, wn = wid & 3;
    const int lr   = lane & 15, hi = lane >> 4;
    const int soff = hi * 128 + lr * 8;      // k-major fragment offset (bhalf)

    const int xcd = blockIdx.x & 7;
    const int i   = blockIdx.x >> 3;
    const int mt  = i & 7;
    const int nt  = xcd * 4 + (i >> 3);
    const int m0 = mt * 256, n0 = nt * 256;

    const bhalf* gA = WcP + (size_t)mt * (NT * BLOB) + tid * 8;
    const bhalf* gB = XtP + (size_t)nt * (NT * BLOB) + tid * 8;

#define STAGE(t) do {                                                   \
        const bhalf* sa_ = gA + (size_t)(t) * BLOB;                     \
        const bhalf* sb_ = gB + (size_t)(t) * BLOB;                     \
        bhalf* da_ = &As[(t) & 3][tid * 8];                             \
        bhalf* db_ = &Bs[(t) & 3][tid * 8];                             \
        GLDS(sa_, da_); GLDS(sa_ + 4096, da_ + 4096);                   \
        GLDS(sb_, db_); GLDS(sb_ + 4096, db_ + 4096);                   \
    } while (0)

    f32x4 acc[8][4] = {};

    STAGE(0); STAGE(1); STAGE(2);

    for (int tt = 0; tt < 44; tt += 4) {
        #pragma unroll
        for (int u = 0; u < 4; ++u) {
            VM8(); SBAR();
            STAGE(tt + u + 3);                        // buf (u+3)&3 static
            compute_tile(&As[u][wm * 4096 + soff], &Bs[u][wn * 2048 + soff], acc);
        }
    }
    // tiles 44..47 (stage 47 at t=44; drain counts 8/8/4/0)
    VM8(); SBAR(); STAGE(47);
    compute_tile(&As[0][wm * 4096 + soff], &Bs[0][wn * 2048 + soff], acc);
    VM8(); SBAR();
    compute_tile(&As[1][wm * 4096 + soff], &Bs[1][wn * 2048 + soff], acc);
    VM4(); SBAR();
    compute_tile(&As[2][wm * 4096 + soff], &Bs[2][wn * 2048 + soff], acc);
    VM0(); SBAR();
    compute_tile(&As[3][wm * 4096 + soff], &Bs[3][wn * 2048 + soff], acc);

    // ---- fused gate epilogue: acc[mi][ni][r] = gate r of hidden j ----
    const int colbase = n0 + wn * 64 + lr;
    float zc[4], zbc[4];
    #pragma unroll
    for (int ni = 0; ni < 4; ++ni) {
        zc[ni]  = z[colbase + ni * 16];
        zbc[ni] = zb[colbase + ni * 16];
    }
    #pragma unroll
    for (int mi = 0; mi < 8; ++mi) {
        const int j = (m0 >> 2) + wm * 32 + mi * 4 + hi;
        const float bf_ = bias[j];
        const float bi_ = bias[512 + j];
        const float bo_ = bias[1024 + j];
        const float bg_ = bias[1536 + j];
        #pragma unroll
        for (int ni = 0; ni < 4; ++ni) {
            const int col = colbase + ni * 16;
            const size_t idx = (size_t)j * BB + col;
            const float cv = c_in[idx];
            const float hv = h_in[idx];
            const float fv = sigmf(acc[mi][ni][0] + bf_);
            const float iv = sigmf(acc[mi][ni][1] + bi_);
            const float ov = sigmf(acc[mi][ni][2] + bo_);
            const float gv = tanhfast(acc[mi][ni][3] + bg_);
            const float ig = iv * gv;
            const float zq = zc[ni], zbq = zbc[ni];
            const float cn = zq * ig + (1.f - zq) * (1.f - zbq) * cv
                           + (1.f - zq) * zbq * (fv * cv + ig);
            const float tc = tanhfast(cn);
            const float hn = (zq + (1.f - zq) * zbq) * ov * tc
                           + (1.f - zq) * (1.f - zbq) * hv;
            out[idx]      = hn;
            out[HB + idx] = cn;
        }
    }
}

// ---------------------------------------------------------------------------
// zhat: row 2048 GEMV over packed Xt (bf16). 256 blocks x 32 cols,
// 8 k-groups per column, LDS reduce.
// ---------------------------------------------------------------------------
__global__ __launch_bounds__(256) void zhat_k(
    const bhalf* __restrict__ XtP, const float* __restrict__ U11,
    const float* __restrict__ U21, const float* __restrict__ W01,
    const float* __restrict__ bias, float* __restrict__ out)
{
    __shared__ float wlds[1536];
    __shared__ float red[8][32];
    const int tid = threadIdx.x;
    for (int idx = tid; idx < 1536; idx += 256) {
        float v;
        if (idx < 512)       v = U11[1048576 + idx];
        else if (idx < 1024) v = U21[1048576 + idx - 512];
        else                 v = W01[1048576 + idx - 1024];
        wlds[idx] = v;
    }
    __syncthreads();

    const int col = tid & 31, kg = tid >> 5;
    const int n = blockIdx.x * 32 + col;
    const int nt = n >> 8, rb = (n >> 4) & 15, lrr = n & 15;
    const bhalf* base = XtP + (size_t)nt * (NT * BLOB) + rb * 512;

    float acc = 0.f;
    for (int kt = kg * 6; kt < kg * 6 + 6; ++kt) {
        #pragma unroll
        for (int hh = 0; hh < 4; ++hh) {
            bf16x8 v = *(const bf16x8*)(base + (size_t)kt * BLOB + hh * 128 + lrr * 8);
            #pragma unroll
            for (int e = 0; e < 8; ++e)
                acc += (float)v[e] * wlds[kt * 32 + hh * 8 + e];
        }
    }
    red[kg][col] = acc;
    __syncthreads();
    if (tid < 32) {
        float s = 0.f;
        #pragma unroll
        for (int k2 = 0; k2 < 8; ++k2) s += red[k2][tid];
        const float v = (s + bias[2048] + 1.f) * 0.5f;
        out[(size_t)2 * HB + blockIdx.x * 32 + tid] = fminf(fmaxf(v, 0.f), 1.f);
    }
}

// ---------------------------------------------------------------------------
extern "C" void kernel_launch(void* const* d_in, const int* in_sizes, int n_in,
                              void* d_out, int out_size, void* d_ws, size_t ws_size,
                              hipStream_t stream) {
    const float* c    = (const float*)d_in[0];
    const float* hb   = (const float*)d_in[1];
    const float* h    = (const float*)d_in[2];
    const float* ht   = (const float*)d_in[3];
    const float* z    = (const float*)d_in[4];
    const float* zb   = (const float*)d_in[5];
    const float* U11  = (const float*)d_in[6];
    const float* U21  = (const float*)d_in[7];
    const float* W01  = (const float*)d_in[8];
    const float* bias = (const float*)d_in[9];
    float* out = (float*)d_out;

    // ws: XtP 32*48*16KB = 25165824 B; WcP 8*48*16KB = 6291456 B
    char* ws = (char*)d_ws;
    bhalf* XtP = (bhalf*)ws;
    bhalf* WcP = (bhalf*)(ws + 25165824);

    prep_x    <<<dim3(48, 32), 256, 0, stream>>>(h, ht, hb, z, zb, XtP);
    prep_w    <<<512, 256, 0, stream>>>(U11, U21, W01, WcP);
    gemm_fused<<<256, 512, 0, stream>>>(WcP, XtP, bias, c, h, z, zb, out);
    zhat_k    <<<256, 256, 0, stream>>>(XtP, U11, U21, W01, bias, out);
}